// Round 5
// baseline (37091.351 us; speedup 1.0000x reference)
//
#include <hip/hip_runtime.h>
#include <math.h>

#define SEQ   512
#define BATCH 256
#define IDIM  256
#define HDIM  512
#define ODIM  256
#define NGROUP 16   // batch groups (bi), 16 rows each
#define GBLK   16   // blocks per group (gj), 32 h-cols each
#define KTOT  768   // concatenated K: h (512) + x (256)

#define OUT_ELEMS ((size_t)SEQ * BATCH * ODIM)
#define HF_OFF OUT_ELEMS
#define CF_OFF (OUT_ELEMS + (size_t)BATCH * HDIM)

#define HBUFS 131072u            // u32 per h buffer: 256 rows * 512 cols (fp32)
#define SPIN_TIMEOUT 200000000ull

typedef __attribute__((ext_vector_type(4))) float f32x4;

// ---- system-coherent accessors (L1/L2-bypassing; kept from round 4) ----
__device__ __forceinline__ unsigned int ld_sys_u32(const unsigned int* p) {
  unsigned int v;
  asm volatile("global_load_dword %0, %1, off sc0 sc1\n\t"
               "s_waitcnt vmcnt(0)"
               : "=v"(v) : "v"((unsigned long long)p) : "memory");
  return v;
}

__device__ __forceinline__ void st_sys_u32(unsigned int* p, unsigned int d) {
  asm volatile("global_store_dword %0, %1, off sc0 sc1"
               : : "v"((unsigned long long)p), "v"(d) : "memory");
}

// 16 consecutive coherent dwords (64B), one wait.
__device__ __forceinline__ void ld16c_sys(const unsigned int* p, unsigned int v[16]) {
  unsigned long long a = (unsigned long long)p;
  asm volatile(
      "global_load_dword %0,  %16, off sc0 sc1\n\t"
      "global_load_dword %1,  %16, off offset:4 sc0 sc1\n\t"
      "global_load_dword %2,  %16, off offset:8 sc0 sc1\n\t"
      "global_load_dword %3,  %16, off offset:12 sc0 sc1\n\t"
      "global_load_dword %4,  %16, off offset:16 sc0 sc1\n\t"
      "global_load_dword %5,  %16, off offset:20 sc0 sc1\n\t"
      "global_load_dword %6,  %16, off offset:24 sc0 sc1\n\t"
      "global_load_dword %7,  %16, off offset:28 sc0 sc1\n\t"
      "global_load_dword %8,  %16, off offset:32 sc0 sc1\n\t"
      "global_load_dword %9,  %16, off offset:36 sc0 sc1\n\t"
      "global_load_dword %10, %16, off offset:40 sc0 sc1\n\t"
      "global_load_dword %11, %16, off offset:44 sc0 sc1\n\t"
      "global_load_dword %12, %16, off offset:48 sc0 sc1\n\t"
      "global_load_dword %13, %16, off offset:52 sc0 sc1\n\t"
      "global_load_dword %14, %16, off offset:56 sc0 sc1\n\t"
      "global_load_dword %15, %16, off offset:60 sc0 sc1\n\t"
      "s_waitcnt vmcnt(0)"
      : "=&v"(v[0]), "=&v"(v[1]), "=&v"(v[2]), "=&v"(v[3]),
        "=&v"(v[4]), "=&v"(v[5]), "=&v"(v[6]), "=&v"(v[7]),
        "=&v"(v[8]), "=&v"(v[9]), "=&v"(v[10]), "=&v"(v[11]),
        "=&v"(v[12]), "=&v"(v[13]), "=&v"(v[14]), "=&v"(v[15])
      : "v"(a)
      : "memory");
}

__device__ __forceinline__ float sigm(float x)   { return 1.f / (1.f + expf(-x)); }
__device__ __forceinline__ float tanh_f(float x) { return 1.f - 2.f / (expf(2.f * x) + 1.f); }

__device__ __forceinline__ void wait_ctr(unsigned int* ctr, unsigned int tgt) {
  unsigned long long t0 = __builtin_amdgcn_s_memrealtime();
  while (ld_sys_u32(ctr) < tgt) {
    __builtin_amdgcn_s_sleep(2);
    if (__builtin_amdgcn_s_memrealtime() - t0 > SPIN_TIMEOUT) break;  // diagnostic bail
  }
  __builtin_amdgcn_fence(__ATOMIC_ACQUIRE, "agent");
}

// ====== ALL-FP32 VALU PROBE (no MFMA anywhere) ======
// Same decomposition/protocol as rounds 3-4. Gate GEMV: 128 gate-rows per block
// (4 types x 32 cols), 2 threads per gate-row (K split 2x384 over KTOT=768),
// weights register-resident fp32. h exchanged as raw fp32.
__global__ void __launch_bounds__(256, 1)
lstm_probe(const float* __restrict__ xs,
           const float* __restrict__ Wih,
           const float* __restrict__ Whh,
           const float* __restrict__ bih,
           const float* __restrict__ bhh,
           const float* __restrict__ Wfc,
           const float* __restrict__ bfc,
           float* __restrict__ out,
           unsigned int* __restrict__ bar,
           unsigned int* __restrict__ hb32)
{
  const int tid = threadIdx.x;
  const int bi  = blockIdx.x & (NGROUP - 1);
  const int gj  = blockIdx.x / NGROUP;
  const int r0  = bi * 16;    // batch row base
  const int hc0 = gj * 32;    // h-col base
  const int oc0 = gj * 16;    // out-col base

  unsigned int* ctr = bar + bi * 32;

  // ---- register-resident fp32 weights: thread (g_idx, half) ----
  const int g_idx = tid >> 1;          // 0..127 : gate-row within block
  const int half  = tid & 1;           // K half: [half*384, half*384+384)
  const int G     = (g_idx >> 5) * HDIM + hc0 + (g_idx & 31);  // global gate row
  f32x4 wreg[96];
#pragma unroll
  for (int k4 = 0; k4 < 96; ++k4) {
    int kg = half * 384 + 4 * k4;
    if (kg < 512) wreg[k4] = *(const f32x4*)(Whh + (size_t)G * HDIM + kg);
    else          wreg[k4] = *(const f32x4*)(Wih + (size_t)G * IDIM + (kg - 512));
  }

  const int rrow = tid >> 4;           // recombine batch-row / out row
  const int rcp  = tid & 15;           // recombine col-pair / out col
  float gb8[4][2];
#pragma unroll
  for (int w = 0; w < 4; ++w)
#pragma unroll
    for (int q = 0; q < 2; ++q) {
      int G2 = w * HDIM + hc0 + 2 * rcp + q;
      gb8[w][q] = bih[G2] + bhh[G2];
    }
  const float fcb = bfc[oc0 + rcp];

  __shared__ float z[16][KTOT];        // [batch 16][ h(512) | x(256) ]  48 KB
  __shared__ float wfc_l[16][516];     // FC weight slice, +4 pad       33 KB
  __shared__ float pg[2][16][128];     // gate partials (K halves)      16 KB
  __shared__ float lds_c[16][32];      // persistent cell state          2 KB

  // ---- one-time staging ----
#pragma unroll
  for (int u = 0; u < 8; ++u) {
    int idx = tid + 256 * u;           // float4 id in 16x512
    int oc = idx >> 7, c4 = idx & 127;
    *(f32x4*)&wfc_l[oc][4 * c4] = *(const f32x4*)(Wfc + (size_t)(oc0 + oc) * HDIM + 4 * c4);
  }
  lds_c[rrow][2 * rcp]     = 0.f;
  lds_c[rrow][2 * rcp + 1] = 0.f;
  __syncthreads();

  const int zr = tid >> 4;             // staging row
  const int cb = (tid & 15) * 32;      // staging col base (32 cols/thread)

#pragma unroll 1
  for (int t = 0; t < SEQ; ++t) {
    if (t > 0) {
      if (tid == 0) wait_ctr(ctr, 16u * (unsigned int)t);
      __syncthreads();
    }
    // ---- stage z: h[t-1] (fp32, coherent) | x[t] ----
    if (t > 0) {
      const unsigned int* p = hb32 + ((unsigned)((t - 1) & 1)) * HBUFS
                            + (unsigned)(r0 + zr) * 512u + (unsigned)cb;
      unsigned int v[32];
      ld16c_sys(p, v);
      ld16c_sys(p + 16, v + 16);
#pragma unroll
      for (int u = 0; u < 32; ++u)
        z[zr][cb + u] = __uint_as_float(v[u]);
    } else {
#pragma unroll
      for (int u = 0; u < 32; ++u)
        z[zr][cb + u] = 0.f;           // h0 = 0
    }
    {
      const float* xt = xs + (size_t)t * BATCH * IDIM;
#pragma unroll
      for (int u = 0; u < 4; ++u) {
        int idx = tid * 4 + u;         // float4 id in 16x64
        int r = idx >> 6, c4 = idx & 63;
        *(f32x4*)&z[r][512 + 4 * c4] = *(const f32x4*)(xt + (size_t)(r0 + r) * IDIM + 4 * c4);
      }
    }
    __syncthreads();

    // ---- gates: acc[r] = sum_k z[r][k]*W[G][k] over this thread's K half ----
    float acc[16];
#pragma unroll
    for (int r = 0; r < 16; ++r) acc[r] = 0.f;
    {
      const f32x4* zp = (const f32x4*)&z[0][0] + (half * 96);
#pragma unroll
      for (int k4 = 0; k4 < 96; ++k4) {
        f32x4 wv = wreg[k4];
#pragma unroll
        for (int r = 0; r < 16; ++r) {
          f32x4 zv = zp[r * 192 + k4];   // z row stride = 192 float4
          acc[r] += wv[0] * zv[0] + wv[1] * zv[1] + wv[2] * zv[2] + wv[3] * zv[3];
        }
      }
    }
#pragma unroll
    for (int r = 0; r < 16; ++r)
      pg[half][r][g_idx] = acc[r];

    // ---- FC head on h[t-1] (z cols 0..511) -> out[t-1][.., oc0+rcp] ----
    float fco = fcb;
    if (t > 0) {
      const f32x4* zp = (const f32x4*)&z[rrow][0];
      const f32x4* wp = (const f32x4*)&wfc_l[rcp][0];
#pragma unroll
      for (int k4 = 0; k4 < 128; ++k4) {
        f32x4 a = zp[k4], b = wp[k4];
        fco += a[0] * b[0] + a[1] * b[1] + a[2] * b[2] + a[3] * b[3];
      }
    }
    __syncthreads();

    // ---- recombine: activations + c/h update ----
    float hn[2], cn[2];
#pragma unroll
    for (int q = 0; q < 2; ++q) {
      int c = 2 * rcp + q;
      float P0 = pg[0][rrow][0 * 32 + c] + pg[1][rrow][0 * 32 + c] + gb8[0][q];
      float P1 = pg[0][rrow][1 * 32 + c] + pg[1][rrow][1 * 32 + c] + gb8[1][q];
      float P2 = pg[0][rrow][2 * 32 + c] + pg[1][rrow][2 * 32 + c] + gb8[2][q];
      float P3 = pg[0][rrow][3 * 32 + c] + pg[1][rrow][3 * 32 + c] + gb8[3][q];
      float ig = sigm(P0), fg = sigm(P1), gg = tanh_f(P2), og = sigm(P3);
      float cc = fg * lds_c[rrow][c] + ig * gg;
      lds_c[rrow][c] = cc;
      cn[q] = cc;
      hn[q] = og * tanh_f(cc);
    }

    if (t > 0)
      out[((size_t)(t - 1) * BATCH + (r0 + rrow)) * ODIM + oc0 + rcp] = fco;
    if (t == SEQ - 1) {
#pragma unroll
      for (int q = 0; q < 2; ++q) {
        size_t hi_ = (size_t)(r0 + rrow) * HDIM + hc0 + 2 * rcp + q;
        out[HF_OFF + hi_] = hn[q];
        out[CF_OFF + hi_] = cn[q];
      }
    }

    // ---- publish h[t] as raw fp32 (coherent stores) ----
    {
      unsigned int pb = ((unsigned)(t & 1)) * HBUFS
                      + (unsigned)(r0 + rrow) * 512u + (unsigned)(hc0 + 2 * rcp);
      st_sys_u32(hb32 + pb,     __float_as_uint(hn[0]));
      st_sys_u32(hb32 + pb + 1, __float_as_uint(hn[1]));
    }
    asm volatile("s_waitcnt vmcnt(0)" ::: "memory");
    __syncthreads();
    if (tid == 0)
      __hip_atomic_fetch_add(ctr, 1u, __ATOMIC_RELEASE, __HIP_MEMORY_SCOPE_SYSTEM);
  }

  // ---- tail: out[SEQ-1] from h[SEQ-1] ----
  if (tid == 0) wait_ctr(ctr, 16u * SEQ);
  __syncthreads();
  {
    const unsigned int* p = hb32 + ((unsigned)((SEQ - 1) & 1)) * HBUFS
                          + (unsigned)(r0 + zr) * 512u + (unsigned)cb;
    unsigned int v[32];
    ld16c_sys(p, v);
    ld16c_sys(p + 16, v + 16);
#pragma unroll
    for (int u = 0; u < 32; ++u)
      z[zr][cb + u] = __uint_as_float(v[u]);
    __syncthreads();
    float fco = fcb;
    const f32x4* zp = (const f32x4*)&z[rrow][0];
    const f32x4* wp = (const f32x4*)&wfc_l[rcp][0];
#pragma unroll
    for (int k4 = 0; k4 < 128; ++k4) {
      f32x4 a = zp[k4], b = wp[k4];
      fco += a[0] * b[0] + a[1] * b[1] + a[2] * b[2] + a[3] * b[3];
    }
    out[((size_t)(SEQ - 1) * BATCH + (r0 + rrow)) * ODIM + oc0 + rcp] = fco;
  }
}

extern "C" void kernel_launch(void* const* d_in, const int* in_sizes, int n_in,
                              void* d_out, int out_size, void* d_ws, size_t ws_size,
                              hipStream_t stream)
{
  const float* xs  = (const float*)d_in[0];
  const float* wih = (const float*)d_in[1];
  const float* whh = (const float*)d_in[2];
  const float* bi_ = (const float*)d_in[3];
  const float* bh_ = (const float*)d_in[4];
  const float* wfc = (const float*)d_in[5];
  const float* bf_ = (const float*)d_in[6];
  float* out = (float*)d_out;

  unsigned int* bar  = (unsigned int*)d_ws;                    // 4 KB barrier area
  unsigned int* hb32 = (unsigned int*)((char*)d_ws + 4096);    // 1 MB fp32 h dbuf

  hipMemsetAsync(d_ws, 0, 4096, stream);  // reset barrier counters each call

  lstm_probe<<<dim3(NGROUP * GBLK), dim3(256), 0, stream>>>(
      xs, wih, whh, bi_, bh_, wfc, bf_, out, bar, hb32);
}

// Round 6
// 11183.946 us; speedup vs baseline: 3.3165x; 3.3165x over previous
//
#include <hip/hip_runtime.h>
#include <math.h>

#define SEQ   512
#define BATCH 256
#define IDIM  256
#define HDIM  512
#define ODIM  256
#define NGROUP 16   // batch groups (bi), 16 rows each
#define GBLK   16   // blocks per group (gj), 32 h-cols each

#define OUT_ELEMS ((size_t)SEQ * BATCH * ODIM)
#define HF_OFF OUT_ELEMS
#define CF_OFF (OUT_ELEMS + (size_t)BATCH * HDIM)

#define HBUFS 131072u            // u32 per h buffer: 256 rows x 512 cols (fp32)
#define SPIN_TIMEOUT 200000000ull

#define H_SCALE 4096.0f
#define H_INV   2.44140625e-4f   // 2^-12
#define HMIN    6.104e-5f        // fp16 min normal
#define ZW      390              // u32 row stride of z planes (384 + 6: bank-spread)

typedef __attribute__((ext_vector_type(8))) _Float16 half8;
typedef __attribute__((ext_vector_type(4))) float f32x4;

__device__ __forceinline__ unsigned short hbits(_Float16 h) {
  return __builtin_bit_cast(unsigned short, h);
}

__device__ __forceinline__ f32x4 mfma_h(half8 a, half8 b, f32x4 c) {
  return __builtin_amdgcn_mfma_f32_16x16x32_f16(a, b, c, 0, 0, 0);
}

// ---- system-coherent accessors (probe-proven) ----
__device__ __forceinline__ unsigned int ld_sys_u32(const unsigned int* p) {
  unsigned int v;
  asm volatile("global_load_dword %0, %1, off sc0 sc1\n\t"
               "s_waitcnt vmcnt(0)"
               : "=v"(v) : "v"((unsigned long long)p) : "memory");
  return v;
}

__device__ __forceinline__ void st_sys_u32(unsigned int* p, unsigned int d) {
  asm volatile("global_store_dword %0, %1, off sc0 sc1"
               : : "v"((unsigned long long)p), "v"(d) : "memory");
}

// 16 consecutive coherent dwords (64B), one wait (probe-proven).
__device__ __forceinline__ void ld16c_sys(const unsigned int* p, unsigned int v[16]) {
  unsigned long long a = (unsigned long long)p;
  asm volatile(
      "global_load_dword %0,  %16, off sc0 sc1\n\t"
      "global_load_dword %1,  %16, off offset:4 sc0 sc1\n\t"
      "global_load_dword %2,  %16, off offset:8 sc0 sc1\n\t"
      "global_load_dword %3,  %16, off offset:12 sc0 sc1\n\t"
      "global_load_dword %4,  %16, off offset:16 sc0 sc1\n\t"
      "global_load_dword %5,  %16, off offset:20 sc0 sc1\n\t"
      "global_load_dword %6,  %16, off offset:24 sc0 sc1\n\t"
      "global_load_dword %7,  %16, off offset:28 sc0 sc1\n\t"
      "global_load_dword %8,  %16, off offset:32 sc0 sc1\n\t"
      "global_load_dword %9,  %16, off offset:36 sc0 sc1\n\t"
      "global_load_dword %10, %16, off offset:40 sc0 sc1\n\t"
      "global_load_dword %11, %16, off offset:44 sc0 sc1\n\t"
      "global_load_dword %12, %16, off offset:48 sc0 sc1\n\t"
      "global_load_dword %13, %16, off offset:52 sc0 sc1\n\t"
      "global_load_dword %14, %16, off offset:56 sc0 sc1\n\t"
      "global_load_dword %15, %16, off offset:60 sc0 sc1\n\t"
      "s_waitcnt vmcnt(0)"
      : "=&v"(v[0]), "=&v"(v[1]), "=&v"(v[2]), "=&v"(v[3]),
        "=&v"(v[4]), "=&v"(v[5]), "=&v"(v[6]), "=&v"(v[7]),
        "=&v"(v[8]), "=&v"(v[9]), "=&v"(v[10]), "=&v"(v[11]),
        "=&v"(v[12]), "=&v"(v[13]), "=&v"(v[14]), "=&v"(v[15])
      : "v"(a)
      : "memory");
}

// Scaled split-2: v = hi + lo*2^-12 + O(2^-23 * v).
__device__ __forceinline__ void split_f(float f, _Float16 &hi, _Float16 &lo) {
  _Float16 a = (_Float16)0.f;
  if (fabsf(f) >= HMIN) a = (_Float16)f;
  float f1 = (float)a;
  hi = a;
  lo = (_Float16)((f - f1) * H_SCALE);
}

__device__ __forceinline__ void split8(const float* __restrict__ p, half8 &hi, half8 &lo) {
  const f32x4 va = *(const f32x4*)p;
  const f32x4 vb = *(const f32x4*)(p + 4);
#pragma unroll
  for (int j = 0; j < 4; ++j) { _Float16 h, l; split_f(va[j], h, l); hi[j] = h; lo[j] = l; }
#pragma unroll
  for (int j = 0; j < 4; ++j) { _Float16 h, l; split_f(vb[j], h, l); hi[4 + j] = h; lo[4 + j] = l; }
}

__device__ __forceinline__ float sigm(float x)   { return 1.f / (1.f + expf(-x)); }
__device__ __forceinline__ float tanh_f(float x) { return 1.f - 2.f / (expf(2.f * x) + 1.f); }

__device__ __forceinline__ void wait_ctr(unsigned int* ctr, unsigned int tgt) {
  unsigned long long t0 = __builtin_amdgcn_s_memrealtime();
  while (ld_sys_u32(ctr) < tgt) {
    __builtin_amdgcn_s_sleep(2);
    if (__builtin_amdgcn_s_memrealtime() - t0 > SPIN_TIMEOUT) break;  // diagnostic bail
  }
  __builtin_amdgcn_fence(__ATOMIC_ACQUIRE, "agent");
}

// Probe skeleton + MFMA split-2 gates/FC. grid=256, block=256=4 waves
// (wave w = gate type w for its 32 h-cols).
__global__ void __launch_bounds__(256, 1)
lstm_mfma(const float* __restrict__ xs,
          const float* __restrict__ Wih,
          const float* __restrict__ Whh,
          const float* __restrict__ bih,
          const float* __restrict__ bhh,
          const float* __restrict__ Wfc,
          const float* __restrict__ bfc,
          float* __restrict__ out,
          unsigned int* __restrict__ bar,
          unsigned int* __restrict__ hb32)
{
  const int tid = threadIdx.x;
  const int w   = tid >> 6;
  const int l   = tid & 63;
  const int lr  = l & 15;     // A row / B,D col
  const int lk  = l >> 4;     // k subgroup

  const int bi  = blockIdx.x & (NGROUP - 1);
  const int gj  = blockIdx.x / NGROUP;
  const int r0  = bi * 16;
  const int hc0 = gj * 32;
  const int oc0 = gj * 16;

  unsigned int* ctr = bar + bi * 32;

  // ---- persistent fp16 split-2 weight fragments over merged K = [h(16 tiles)|x(8 tiles)] ----
  half8 wz1[24][2], wz2[24][2];
#pragma unroll
  for (int kk = 0; kk < 24; ++kk)
#pragma unroll
    for (int nt = 0; nt < 2; ++nt) {
      int g = w * HDIM + hc0 + nt * 16 + lr;
      const float* src = (kk < 16)
          ? (Whh + (size_t)g * HDIM + kk * 32 + lk * 8)
          : (Wih + (size_t)g * IDIM + (kk - 16) * 32 + lk * 8);
      split8(src, wz1[kk][nt], wz2[kk][nt]);
    }
  half8 wfc1[4];   // FC weight hi-level only (error non-recurrent, ~5e-5)
#pragma unroll
  for (int q = 0; q < 4; ++q) {
    half8 hi, lo;
    split8(Wfc + (size_t)(oc0 + lr) * HDIM + (w * 4 + q) * 32 + lk * 8, hi, lo);
    wfc1[q] = hi;
  }
  float gb[2];
#pragma unroll
  for (int nt = 0; nt < 2; ++nt) {
    int g = w * HDIM + hc0 + nt * 16 + lr;
    gb[nt] = bih[g] + bhh[g];
  }

  const int rrow = tid >> 4;
  const int rcp  = tid & 15;
  const float fcb = bfc[oc0 + rcp];

  __shared__ unsigned int z1[16][ZW];   // hi plane: [h 256 u32 | x 128 u32], packed fp16 pairs
  __shared__ unsigned int z2[16][ZW];   // lo plane (2^12-scaled residual)
  __shared__ float lds_g[4][16][32];
  __shared__ float lds_fc[4][16][16];
  __shared__ float lds_c[16][32];

  lds_c[rrow][2 * rcp]     = 0.f;
  lds_c[rrow][2 * rcp + 1] = 0.f;

  const int srow = tid & 15;   // staging row
  const int schk = tid >> 4;   // staging chunk

#pragma unroll 1
  for (int t = 0; t < SEQ; ++t) {
    if (t > 0) {
      if (tid == 0) wait_ctr(ctr, 16u * (unsigned int)t);
      __syncthreads();
    }
    // ---- stage h[t-1]: fp32 coherent load -> split -> two fp16 planes ----
    if (t > 0) {
      const unsigned int* p = hb32 + ((unsigned)((t - 1) & 1)) * HBUFS
                            + (unsigned)(r0 + srow) * 512u + (unsigned)(schk * 32);
#pragma unroll
      for (int pass = 0; pass < 2; ++pass) {
        unsigned int v[16];
        ld16c_sys(p + 16 * pass, v);
#pragma unroll
        for (int i = 0; i < 8; ++i) {
          _Float16 h0, l0, h1, l1;
          split_f(__uint_as_float(v[2 * i]),     h0, l0);
          split_f(__uint_as_float(v[2 * i + 1]), h1, l1);
          int c = schk * 16 + 8 * pass + i;
          z1[srow][c] = (unsigned int)hbits(h0) | ((unsigned int)hbits(h1) << 16);
          z2[srow][c] = (unsigned int)hbits(l0) | ((unsigned int)hbits(l1) << 16);
        }
      }
    } else {
#pragma unroll
      for (int i = 0; i < 16; ++i) {
        z1[srow][schk * 16 + i] = 0u;
        z2[srow][schk * 16 + i] = 0u;
      }
    }
    // ---- stage x[t] (plain loads) -> split -> planes at u32 cols 256+ ----
    {
      const float* xt = xs + (size_t)t * BATCH * IDIM + (size_t)(r0 + srow) * IDIM + schk * 16;
#pragma unroll
      for (int i = 0; i < 8; ++i) {
        _Float16 h0, l0, h1, l1;
        split_f(xt[2 * i],     h0, l0);
        split_f(xt[2 * i + 1], h1, l1);
        int c = 256 + schk * 8 + i;
        z1[srow][c] = (unsigned int)hbits(h0) | ((unsigned int)hbits(h1) << 16);
        z2[srow][c] = (unsigned int)hbits(l0) | ((unsigned int)hbits(l1) << 16);
      }
    }
    __syncthreads();

    // ---- gates: 24 K-tiles x (2 n-tiles) x 3 split-products ----
    f32x4 ga0 = {gb[0], gb[0], gb[0], gb[0]};
    f32x4 ga1 = {gb[1], gb[1], gb[1], gb[1]};
    f32x4 gl0 = {0.f, 0.f, 0.f, 0.f};
    f32x4 gl1 = {0.f, 0.f, 0.f, 0.f};
    const unsigned short* zr1 = (const unsigned short*)&z1[lr][0];
    const unsigned short* zr2 = (const unsigned short*)&z2[lr][0];
#pragma unroll
    for (int kk = 0; kk < 24; ++kk) {
      half8 a1 = *(const half8*)(zr1 + kk * 32 + lk * 8);
      half8 a2 = *(const half8*)(zr2 + kk * 32 + lk * 8);
      ga0 = mfma_h(a1, wz1[kk][0], ga0);
      gl0 = mfma_h(a2, wz1[kk][0], gl0);
      gl0 = mfma_h(a1, wz2[kk][0], gl0);
      ga1 = mfma_h(a1, wz1[kk][1], ga1);
      gl1 = mfma_h(a2, wz1[kk][1], gl1);
      gl1 = mfma_h(a1, wz2[kk][1], gl1);
    }

    // ---- FC head on h[t-1] (K-quarter per wave, same fragment maps) ----
    f32x4 f1a = {0.f, 0.f, 0.f, 0.f};
    f32x4 f2a = {0.f, 0.f, 0.f, 0.f};
    if (t > 0) {
#pragma unroll
      for (int q = 0; q < 4; ++q) {
        int kk = w * 4 + q;
        half8 a1 = *(const half8*)(zr1 + kk * 32 + lk * 8);
        half8 a2 = *(const half8*)(zr2 + kk * 32 + lk * 8);
        f1a = mfma_h(a1, wfc1[q], f1a);
        f2a = mfma_h(a2, wfc1[q], f2a);
      }
    }

    // ---- fold + exchange ----
#pragma unroll
    for (int j = 0; j < 4; ++j) {
      lds_g[w][lk * 4 + j][lr]      = ga0[j] + gl0[j] * H_INV;
      lds_g[w][lk * 4 + j][16 + lr] = ga1[j] + gl1[j] * H_INV;
      lds_fc[w][lk * 4 + j][lr]     = f1a[j] + f2a[j] * H_INV;
    }
    __syncthreads();

    // ---- recombine (probe-identical) ----
    float hn[2], cn[2];
#pragma unroll
    for (int q = 0; q < 2; ++q) {
      int c = 2 * rcp + q;
      float ig = sigm(lds_g[0][rrow][c]);
      float fg = sigm(lds_g[1][rrow][c]);
      float gg = tanh_f(lds_g[2][rrow][c]);
      float og = sigm(lds_g[3][rrow][c]);
      float cc = fg * lds_c[rrow][c] + ig * gg;
      lds_c[rrow][c] = cc;
      cn[q] = cc;
      hn[q] = og * tanh_f(cc);
    }

    if (t > 0) {
      float o = lds_fc[0][rrow][rcp] + lds_fc[1][rrow][rcp]
              + lds_fc[2][rrow][rcp] + lds_fc[3][rrow][rcp] + fcb;
      out[((size_t)(t - 1) * BATCH + (r0 + rrow)) * ODIM + oc0 + rcp] = o;
    }
    if (t == SEQ - 1) {
#pragma unroll
      for (int q = 0; q < 2; ++q) {
        size_t hi_ = (size_t)(r0 + rrow) * HDIM + hc0 + 2 * rcp + q;
        out[HF_OFF + hi_] = hn[q];
        out[CF_OFF + hi_] = cn[q];
      }
    }

    // ---- publish h[t] fp32 (probe-identical) ----
    {
      unsigned int pb = ((unsigned)(t & 1)) * HBUFS
                      + (unsigned)(r0 + rrow) * 512u + (unsigned)(hc0 + 2 * rcp);
      st_sys_u32(hb32 + pb,     __float_as_uint(hn[0]));
      st_sys_u32(hb32 + pb + 1, __float_as_uint(hn[1]));
    }
    asm volatile("s_waitcnt vmcnt(0)" ::: "memory");
    __syncthreads();
    if (tid == 0)
      __hip_atomic_fetch_add(ctr, 1u, __ATOMIC_RELEASE, __HIP_MEMORY_SCOPE_SYSTEM);
  }

  // ---- tail: out[SEQ-1] from h[SEQ-1] ----
  if (tid == 0) wait_ctr(ctr, 16u * SEQ);
  __syncthreads();
  {
    const unsigned int* p = hb32 + ((unsigned)((SEQ - 1) & 1)) * HBUFS
                          + (unsigned)(r0 + srow) * 512u + (unsigned)(schk * 32);
#pragma unroll
    for (int pass = 0; pass < 2; ++pass) {
      unsigned int v[16];
      ld16c_sys(p + 16 * pass, v);
#pragma unroll
      for (int i = 0; i < 8; ++i) {
        _Float16 h0, l0, h1, l1;
        split_f(__uint_as_float(v[2 * i]),     h0, l0);
        split_f(__uint_as_float(v[2 * i + 1]), h1, l1);
        int c = schk * 16 + 8 * pass + i;
        z1[srow][c] = (unsigned int)hbits(h0) | ((unsigned int)hbits(h1) << 16);
        z2[srow][c] = (unsigned int)hbits(l0) | ((unsigned int)hbits(l1) << 16);
      }
    }
    __syncthreads();
    f32x4 f1a = {0.f, 0.f, 0.f, 0.f};
    f32x4 f2a = {0.f, 0.f, 0.f, 0.f};
    const unsigned short* zr1 = (const unsigned short*)&z1[lr][0];
    const unsigned short* zr2 = (const unsigned short*)&z2[lr][0];
#pragma unroll
    for (int q = 0; q < 4; ++q) {
      int kk = w * 4 + q;
      half8 a1 = *(const half8*)(zr1 + kk * 32 + lk * 8);
      half8 a2 = *(const half8*)(zr2 + kk * 32 + lk * 8);
      f1a = mfma_h(a1, wfc1[q], f1a);
      f2a = mfma_h(a2, wfc1[q], f2a);
    }
#pragma unroll
    for (int j = 0; j < 4; ++j)
      lds_fc[w][lk * 4 + j][lr] = f1a[j] + f2a[j] * H_INV;
    __syncthreads();
    float o = lds_fc[0][rrow][rcp] + lds_fc[1][rrow][rcp]
            + lds_fc[2][rrow][rcp] + lds_fc[3][rrow][rcp] + fcb;
    out[((size_t)(SEQ - 1) * BATCH + (r0 + rrow)) * ODIM + oc0 + rcp] = o;
  }
}

extern "C" void kernel_launch(void* const* d_in, const int* in_sizes, int n_in,
                              void* d_out, int out_size, void* d_ws, size_t ws_size,
                              hipStream_t stream)
{
  const float* xs  = (const float*)d_in[0];
  const float* wih = (const float*)d_in[1];
  const float* whh = (const float*)d_in[2];
  const float* bi_ = (const float*)d_in[3];
  const float* bh_ = (const float*)d_in[4];
  const float* wfc = (const float*)d_in[5];
  const float* bf_ = (const float*)d_in[6];
  float* out = (float*)d_out;

  unsigned int* bar  = (unsigned int*)d_ws;                    // 4 KB barrier area
  unsigned int* hb32 = (unsigned int*)((char*)d_ws + 4096);    // 1 MB fp32 h dbuf

  hipMemsetAsync(d_ws, 0, 4096, stream);  // reset barrier counters each call

  lstm_mfma<<<dim3(NGROUP * GBLK), dim3(256), 0, stream>>>(
      xs, wih, whh, bi_, bh_, wfc, bf_, out, bar, hb32);
}

// Round 7
// 5641.039 us; speedup vs baseline: 6.5753x; 1.9826x over previous
//
#include <hip/hip_runtime.h>
#include <math.h>

#define SEQ   512
#define BATCH 256
#define IDIM  256
#define HDIM  512
#define ODIM  256
#define NGROUP 16   // batch groups (bi), 16 rows each
#define GBLK   16   // blocks per group (gj), 32 h-cols each

#define OUT_ELEMS ((size_t)SEQ * BATCH * ODIM)
#define HF_OFF OUT_ELEMS
#define CF_OFF (OUT_ELEMS + (size_t)BATCH * HDIM)

#define HBUFS 131072u            // u32 per h buffer: 256 rows x 512 cols (fp32)
#define SPIN_TIMEOUT 200000000ull

#define H_SCALE 4096.0f
#define H_INV   2.44140625e-4f   // 2^-12
#define HMIN    6.104e-5f        // fp16 min normal
#define ZW      390              // u32 row stride of z planes (384 + 6: bank-spread)

typedef __attribute__((ext_vector_type(8))) _Float16 half8;
typedef __attribute__((ext_vector_type(4))) float f32x4;
typedef __attribute__((ext_vector_type(4))) unsigned int uint4v;
typedef __attribute__((ext_vector_type(2))) unsigned int uint2v;

__device__ __forceinline__ unsigned short hbits(_Float16 h) {
  return __builtin_bit_cast(unsigned short, h);
}

__device__ __forceinline__ f32x4 mfma_h(half8 a, half8 b, f32x4 c) {
  return __builtin_amdgcn_mfma_f32_16x16x32_f16(a, b, c, 0, 0, 0);
}

// ---- system-coherent (cache-bypassing) accessors; NO cache-maintenance fences ----
__device__ __forceinline__ unsigned int ld_sys_u32(const unsigned int* p) {
  unsigned int v;
  asm volatile("global_load_dword %0, %1, off sc0 sc1\n\t"
               "s_waitcnt vmcnt(0)"
               : "=v"(v) : "v"((unsigned long long)p) : "memory");
  return v;
}

__device__ __forceinline__ void st_sys_u64(unsigned int* p, uint2v d) {
  asm volatile("global_store_dwordx2 %0, %1, off sc0 sc1"
               : : "v"((unsigned long long)p), "v"(d) : "memory");
}

// Relaxed system-scope atomic add (no return, no L2 writeback/invalidate).
// Ordering vs the h payload is provided by the explicit vmcnt(0) drain before it.
__device__ __forceinline__ void atomic_add_sys(unsigned int* p, unsigned int v) {
  asm volatile("global_atomic_add %0, %1, off sc1"
               : : "v"((unsigned long long)p), "v"(v) : "memory");
}

// 32 consecutive coherent u32 (128B) as 8x dwordx4, ONE vmcnt(0) inside the block.
__device__ __forceinline__ void ld_h128x8_sys(const unsigned int* p, uint4v v[8]) {
  asm volatile(
      "global_load_dwordx4 %0, %8, off sc0 sc1\n\t"
      "global_load_dwordx4 %1, %8, off offset:16 sc0 sc1\n\t"
      "global_load_dwordx4 %2, %8, off offset:32 sc0 sc1\n\t"
      "global_load_dwordx4 %3, %8, off offset:48 sc0 sc1\n\t"
      "global_load_dwordx4 %4, %8, off offset:64 sc0 sc1\n\t"
      "global_load_dwordx4 %5, %8, off offset:80 sc0 sc1\n\t"
      "global_load_dwordx4 %6, %8, off offset:96 sc0 sc1\n\t"
      "global_load_dwordx4 %7, %8, off offset:112 sc0 sc1\n\t"
      "s_waitcnt vmcnt(0)"
      : "=&v"(v[0]), "=&v"(v[1]), "=&v"(v[2]), "=&v"(v[3]),
        "=&v"(v[4]), "=&v"(v[5]), "=&v"(v[6]), "=&v"(v[7])
      : "v"((unsigned long long)p)
      : "memory");
}

// Scaled split-2: v = hi + lo*2^-12 + O(2^-23 * v).
__device__ __forceinline__ void split_f(float f, _Float16 &hi, _Float16 &lo) {
  _Float16 a = (_Float16)0.f;
  if (fabsf(f) >= HMIN) a = (_Float16)f;
  float f1 = (float)a;
  hi = a;
  lo = (_Float16)((f - f1) * H_SCALE);
}

__device__ __forceinline__ void split8(const float* __restrict__ p, half8 &hi, half8 &lo) {
  const f32x4 va = *(const f32x4*)p;
  const f32x4 vb = *(const f32x4*)(p + 4);
#pragma unroll
  for (int j = 0; j < 4; ++j) { _Float16 h, l; split_f(va[j], h, l); hi[j] = h; lo[j] = l; }
#pragma unroll
  for (int j = 0; j < 4; ++j) { _Float16 h, l; split_f(vb[j], h, l); hi[4 + j] = h; lo[4 + j] = l; }
}

__device__ __forceinline__ float sigm(float x)   { return 1.f / (1.f + expf(-x)); }
__device__ __forceinline__ float tanh_f(float x) { return 1.f - 2.f / (expf(2.f * x) + 1.f); }

// Spin without any cache-maintenance fence: the payload loads that follow are
// sc0sc1 (bypassing), so observing the flag is sufficient.
__device__ __forceinline__ void wait_ctr(unsigned int* ctr, unsigned int tgt) {
  unsigned long long t0 = __builtin_amdgcn_s_memrealtime();
  while (ld_sys_u32(ctr) < tgt) {
    __builtin_amdgcn_s_sleep(1);
    if (__builtin_amdgcn_s_memrealtime() - t0 > SPIN_TIMEOUT) break;  // diagnostic bail
  }
}

// Proven round-6 skeleton, fence-free protocol. grid=256, block=256=4 waves
// (wave w = gate type w for its 32 h-cols).
__global__ void __launch_bounds__(256, 1)
lstm_mfma(const float* __restrict__ xs,
          const float* __restrict__ Wih,
          const float* __restrict__ Whh,
          const float* __restrict__ bih,
          const float* __restrict__ bhh,
          const float* __restrict__ Wfc,
          const float* __restrict__ bfc,
          float* __restrict__ out,
          unsigned int* __restrict__ bar,
          unsigned int* __restrict__ hb32)
{
  const int tid = threadIdx.x;
  const int w   = tid >> 6;
  const int l   = tid & 63;
  const int lr  = l & 15;     // A row / B,D col
  const int lk  = l >> 4;     // k subgroup

  const int bi  = blockIdx.x & (NGROUP - 1);
  const int gj  = blockIdx.x / NGROUP;
  const int r0  = bi * 16;
  const int hc0 = gj * 32;
  const int oc0 = gj * 16;

  unsigned int* ctr = bar + bi * 32;

  // ---- persistent fp16 split-2 weight fragments, merged K = [h 16 tiles | x 8 tiles] ----
  half8 wz1[24][2], wz2[24][2];
#pragma unroll
  for (int kk = 0; kk < 24; ++kk)
#pragma unroll
    for (int nt = 0; nt < 2; ++nt) {
      int g = w * HDIM + hc0 + nt * 16 + lr;
      const float* src = (kk < 16)
          ? (Whh + (size_t)g * HDIM + kk * 32 + lk * 8)
          : (Wih + (size_t)g * IDIM + (kk - 16) * 32 + lk * 8);
      split8(src, wz1[kk][nt], wz2[kk][nt]);
    }
  half8 wfc1[4];   // FC weight hi-level only (error non-recurrent)
#pragma unroll
  for (int q = 0; q < 4; ++q) {
    half8 hi, lo;
    split8(Wfc + (size_t)(oc0 + lr) * HDIM + (w * 4 + q) * 32 + lk * 8, hi, lo);
    wfc1[q] = hi;
  }
  float gb[2];
#pragma unroll
  for (int nt = 0; nt < 2; ++nt) {
    int g = w * HDIM + hc0 + nt * 16 + lr;
    gb[nt] = bih[g] + bhh[g];
  }

  const int rrow = tid >> 4;
  const int rcp  = tid & 15;
  const float fcb = bfc[oc0 + rcp];

  __shared__ unsigned int z1[16][ZW];   // hi plane: [h 256 u32 | x 128 u32] fp16 pairs
  __shared__ unsigned int z2[16][ZW];   // lo plane (2^12-scaled residual)
  __shared__ float lds_g[4][16][32];
  __shared__ float lds_fc[4][16][16];
  __shared__ float lds_c[16][32];

  lds_c[rrow][2 * rcp]     = 0.f;
  lds_c[rrow][2 * rcp + 1] = 0.f;

  const int srow = tid & 15;   // staging row
  const int schk = tid >> 4;   // staging chunk

#pragma unroll 1
  for (int t = 0; t < SEQ; ++t) {
    // ---- stage x[t] FIRST (independent of the h-wait; cached loads) ----
    {
      const float* xt = xs + (size_t)t * BATCH * IDIM + (size_t)(r0 + srow) * IDIM + schk * 16;
#pragma unroll
      for (int i = 0; i < 8; ++i) {
        _Float16 h0, l0, h1, l1;
        split_f(xt[2 * i],     h0, l0);
        split_f(xt[2 * i + 1], h1, l1);
        int c = 256 + schk * 8 + i;
        z1[srow][c] = (unsigned int)hbits(h0) | ((unsigned int)hbits(h1) << 16);
        z2[srow][c] = (unsigned int)hbits(l0) | ((unsigned int)hbits(l1) << 16);
      }
    }

    // ---- wait for h[t-1], then stage it (one 8x dwordx4 coherent burst) ----
    if (t > 0) {
      if (tid == 0) wait_ctr(ctr, 16u * (unsigned int)t);
      __syncthreads();
      const unsigned int* p = hb32 + ((unsigned)((t - 1) & 1)) * HBUFS
                            + (unsigned)(r0 + srow) * 512u + (unsigned)(schk * 32);
      uint4v v[8];
      ld_h128x8_sys(p, v);
#pragma unroll
      for (int j = 0; j < 16; ++j) {
        _Float16 h0, l0, h1, l1;
        split_f(__uint_as_float(v[j >> 1][(j & 1) * 2]),     h0, l0);
        split_f(__uint_as_float(v[j >> 1][(j & 1) * 2 + 1]), h1, l1);
        int c = schk * 16 + j;
        z1[srow][c] = (unsigned int)hbits(h0) | ((unsigned int)hbits(h1) << 16);
        z2[srow][c] = (unsigned int)hbits(l0) | ((unsigned int)hbits(l1) << 16);
      }
    } else {
#pragma unroll
      for (int i = 0; i < 16; ++i) {
        z1[srow][schk * 16 + i] = 0u;
        z2[srow][schk * 16 + i] = 0u;
      }
    }
    __syncthreads();

    // ---- gates: 24 K-tiles x 2 n-tiles x 3 split-products ----
    f32x4 ga0 = {gb[0], gb[0], gb[0], gb[0]};
    f32x4 ga1 = {gb[1], gb[1], gb[1], gb[1]};
    f32x4 gl0 = {0.f, 0.f, 0.f, 0.f};
    f32x4 gl1 = {0.f, 0.f, 0.f, 0.f};
    const unsigned short* zr1 = (const unsigned short*)&z1[lr][0];
    const unsigned short* zr2 = (const unsigned short*)&z2[lr][0];
#pragma unroll
    for (int kk = 0; kk < 24; ++kk) {
      half8 a1 = *(const half8*)(zr1 + kk * 32 + lk * 8);
      half8 a2 = *(const half8*)(zr2 + kk * 32 + lk * 8);
      ga0 = mfma_h(a1, wz1[kk][0], ga0);
      gl0 = mfma_h(a2, wz1[kk][0], gl0);
      gl0 = mfma_h(a1, wz2[kk][0], gl0);
      ga1 = mfma_h(a1, wz1[kk][1], ga1);
      gl1 = mfma_h(a2, wz1[kk][1], gl1);
      gl1 = mfma_h(a1, wz2[kk][1], gl1);
    }

    // ---- FC head on h[t-1] (K-quarter per wave) ----
    f32x4 f1a = {0.f, 0.f, 0.f, 0.f};
    f32x4 f2a = {0.f, 0.f, 0.f, 0.f};
    if (t > 0) {
#pragma unroll
      for (int q = 0; q < 4; ++q) {
        int kk = w * 4 + q;
        half8 a1 = *(const half8*)(zr1 + kk * 32 + lk * 8);
        half8 a2 = *(const half8*)(zr2 + kk * 32 + lk * 8);
        f1a = mfma_h(a1, wfc1[q], f1a);
        f2a = mfma_h(a2, wfc1[q], f2a);
      }
    }

    // ---- fold + exchange ----
#pragma unroll
    for (int j = 0; j < 4; ++j) {
      lds_g[w][lk * 4 + j][lr]      = ga0[j] + gl0[j] * H_INV;
      lds_g[w][lk * 4 + j][16 + lr] = ga1[j] + gl1[j] * H_INV;
      lds_fc[w][lk * 4 + j][lr]     = f1a[j] + f2a[j] * H_INV;
    }
    __syncthreads();

    // ---- recombine ----
    float hn[2], cn[2];
#pragma unroll
    for (int q = 0; q < 2; ++q) {
      int c = 2 * rcp + q;
      float ig = sigm(lds_g[0][rrow][c]);
      float fg = sigm(lds_g[1][rrow][c]);
      float gg = tanh_f(lds_g[2][rrow][c]);
      float og = sigm(lds_g[3][rrow][c]);
      float cc = fg * lds_c[rrow][c] + ig * gg;
      lds_c[rrow][c] = cc;
      cn[q] = cc;
      hn[q] = og * tanh_f(cc);
    }

    // ---- publish h[t] first (critical path), flag, THEN out stores ----
    {
      unsigned int pb = ((unsigned)(t & 1)) * HBUFS
                      + (unsigned)(r0 + rrow) * 512u + (unsigned)(hc0 + 2 * rcp);
      uint2v d;
      d[0] = __float_as_uint(hn[0]);
      d[1] = __float_as_uint(hn[1]);
      st_sys_u64(hb32 + pb, d);
    }
    asm volatile("s_waitcnt vmcnt(0)" ::: "memory");  // h stores at coherence point
    __syncthreads();                                   // all waves drained
    if (tid == 0) atomic_add_sys(ctr, 1u);             // relaxed: no cache maintenance

    if (t > 0) {
      float o = lds_fc[0][rrow][rcp] + lds_fc[1][rrow][rcp]
              + lds_fc[2][rrow][rcp] + lds_fc[3][rrow][rcp] + fcb;
      out[((size_t)(t - 1) * BATCH + (r0 + rrow)) * ODIM + oc0 + rcp] = o;
    }
    if (t == SEQ - 1) {
#pragma unroll
      for (int q = 0; q < 2; ++q) {
        size_t hi_ = (size_t)(r0 + rrow) * HDIM + hc0 + 2 * rcp + q;
        out[HF_OFF + hi_] = hn[q];
        out[CF_OFF + hi_] = cn[q];
      }
    }
  }

  // ---- tail: out[SEQ-1] from h[SEQ-1] ----
  if (tid == 0) wait_ctr(ctr, 16u * SEQ);
  __syncthreads();
  {
    const unsigned int* p = hb32 + ((unsigned)((SEQ - 1) & 1)) * HBUFS
                          + (unsigned)(r0 + srow) * 512u + (unsigned)(schk * 32);
    uint4v v[8];
    ld_h128x8_sys(p, v);
#pragma unroll
    for (int j = 0; j < 16; ++j) {
      _Float16 h0, l0, h1, l1;
      split_f(__uint_as_float(v[j >> 1][(j & 1) * 2]),     h0, l0);
      split_f(__uint_as_float(v[j >> 1][(j & 1) * 2 + 1]), h1, l1);
      int c = schk * 16 + j;
      z1[srow][c] = (unsigned int)hbits(h0) | ((unsigned int)hbits(h1) << 16);
      z2[srow][c] = (unsigned int)hbits(l0) | ((unsigned int)hbits(l1) << 16);
    }
    __syncthreads();
    f32x4 f1a = {0.f, 0.f, 0.f, 0.f};
    f32x4 f2a = {0.f, 0.f, 0.f, 0.f};
    const unsigned short* zr1 = (const unsigned short*)&z1[lr][0];
    const unsigned short* zr2 = (const unsigned short*)&z2[lr][0];
#pragma unroll
    for (int q = 0; q < 4; ++q) {
      int kk = w * 4 + q;
      half8 a1 = *(const half8*)(zr1 + kk * 32 + lk * 8);
      half8 a2 = *(const half8*)(zr2 + kk * 32 + lk * 8);
      f1a = mfma_h(a1, wfc1[q], f1a);
      f2a = mfma_h(a2, wfc1[q], f2a);
    }
#pragma unroll
    for (int j = 0; j < 4; ++j)
      lds_fc[w][lk * 4 + j][lr] = f1a[j] + f2a[j] * H_INV;
    __syncthreads();
    float o = lds_fc[0][rrow][rcp] + lds_fc[1][rrow][rcp]
            + lds_fc[2][rrow][rcp] + lds_fc[3][rrow][rcp] + fcb;
    out[((size_t)(SEQ - 1) * BATCH + (r0 + rrow)) * ODIM + oc0 + rcp] = o;
  }
}

extern "C" void kernel_launch(void* const* d_in, const int* in_sizes, int n_in,
                              void* d_out, int out_size, void* d_ws, size_t ws_size,
                              hipStream_t stream)
{
  const float* xs  = (const float*)d_in[0];
  const float* wih = (const float*)d_in[1];
  const float* whh = (const float*)d_in[2];
  const float* bi_ = (const float*)d_in[3];
  const float* bh_ = (const float*)d_in[4];
  const float* wfc = (const float*)d_in[5];
  const float* bf_ = (const float*)d_in[6];
  float* out = (float*)d_out;

  unsigned int* bar  = (unsigned int*)d_ws;                    // 4 KB barrier area
  unsigned int* hb32 = (unsigned int*)((char*)d_ws + 4096);    // 1 MB fp32 h dbuf

  hipMemsetAsync(d_ws, 0, 4096, stream);  // reset barrier counters each call

  lstm_mfma<<<dim3(NGROUP * GBLK), dim3(256), 0, stream>>>(
      xs, wih, whh, bi_, bh_, wfc, bf_, out, bar, hb32);
}

// Round 8
// 4956.060 us; speedup vs baseline: 7.4840x; 1.1382x over previous
//
#include <hip/hip_runtime.h>
#include <math.h>

#define SEQ   512
#define BATCH 256
#define IDIM  256
#define HDIM  512
#define ODIM  256
#define NGROUP 16   // batch groups (bi), 16 rows each
#define GBLK   16   // blocks per group (gj), 32 h-cols each

#define OUT_ELEMS ((size_t)SEQ * BATCH * ODIM)
#define HF_OFF OUT_ELEMS
#define CF_OFF (OUT_ELEMS + (size_t)BATCH * HDIM)

// h exchange buffer: [2 bufs][2 planes][256 rows][256 u32 fp16-pair words]
#define HPLANE     65536u
#define HBUFSTRIDE 131072u
#define SPIN_TIMEOUT 200000000ull

#define H_SCALE 4096.0f
#define H_INV   2.44140625e-4f   // 2^-12
#define HMIN    6.104e-5f        // fp16 min normal
#define ZW      390              // u32 row stride of z planes (bank-spread)

typedef __attribute__((ext_vector_type(8))) _Float16 half8;
typedef __attribute__((ext_vector_type(4))) float f32x4;
typedef __attribute__((ext_vector_type(4))) unsigned int uint4v;

__device__ __forceinline__ unsigned short hbits(_Float16 h) {
  return __builtin_bit_cast(unsigned short, h);
}

__device__ __forceinline__ f32x4 mfma_h(half8 a, half8 b, f32x4 c) {
  return __builtin_amdgcn_mfma_f32_16x16x32_f16(a, b, c, 0, 0, 0);
}

// ---- system-coherent (cache-bypassing) accessors ----
__device__ __forceinline__ unsigned int ld_sys_u32(const unsigned int* p) {
  unsigned int v;
  asm volatile("global_load_dword %0, %1, off sc0 sc1\n\t"
               "s_waitcnt vmcnt(0)"
               : "=v"(v) : "v"((unsigned long long)p) : "memory");
  return v;
}

__device__ __forceinline__ void st_sys_u32(unsigned int* p, unsigned int d) {
  asm volatile("global_store_dword %0, %1, off sc0 sc1"
               : : "v"((unsigned long long)p), "v"(d) : "memory");
}

// Two 64B plane slices (hi, lo) in one burst, single vmcnt(0).
__device__ __forceinline__ void ld_2x64_sys(const unsigned int* p0, const unsigned int* p1,
                                            uint4v a[4], uint4v b[4]) {
  asm volatile(
      "global_load_dwordx4 %0, %8, off sc0 sc1\n\t"
      "global_load_dwordx4 %1, %8, off offset:16 sc0 sc1\n\t"
      "global_load_dwordx4 %2, %8, off offset:32 sc0 sc1\n\t"
      "global_load_dwordx4 %3, %8, off offset:48 sc0 sc1\n\t"
      "global_load_dwordx4 %4, %9, off sc0 sc1\n\t"
      "global_load_dwordx4 %5, %9, off offset:16 sc0 sc1\n\t"
      "global_load_dwordx4 %6, %9, off offset:32 sc0 sc1\n\t"
      "global_load_dwordx4 %7, %9, off offset:48 sc0 sc1\n\t"
      "s_waitcnt vmcnt(0)"
      : "=&v"(a[0]), "=&v"(a[1]), "=&v"(a[2]), "=&v"(a[3]),
        "=&v"(b[0]), "=&v"(b[1]), "=&v"(b[2]), "=&v"(b[3])
      : "v"((unsigned long long)p0), "v"((unsigned long long)p1)
      : "memory");
}

// Scaled split-2: v = hi + lo*2^-12 + O(2^-23 * v).
__device__ __forceinline__ void split_f(float f, _Float16 &hi, _Float16 &lo) {
  _Float16 a = (_Float16)0.f;
  if (fabsf(f) >= HMIN) a = (_Float16)f;
  float f1 = (float)a;
  hi = a;
  lo = (_Float16)((f - f1) * H_SCALE);
}

__device__ __forceinline__ float sigm(float x)   { return 1.f / (1.f + expf(-x)); }
__device__ __forceinline__ float tanh_f(float x) { return 1.f - 2.f / (expf(2.f * x) + 1.f); }

// Per-thread tag poll (continuous; diagnostic timeout, not a hang).
__device__ __forceinline__ void wait_tag(const unsigned int* tp, unsigned int tgt) {
  unsigned long long t0 = __builtin_amdgcn_s_memrealtime();
  while (ld_sys_u32(tp) < tgt) {
    if (__builtin_amdgcn_s_memrealtime() - t0 > SPIN_TIMEOUT) break;
  }
}

// Protocol v2: per-producer tags + producer-side split publish.
// grid=256, block=256=4 waves (wave w = gate type w for its 32 h-cols).
__global__ void __launch_bounds__(256, 1)
lstm_mfma(const float* __restrict__ xs,
          const float* __restrict__ Wih,
          const float* __restrict__ Whh,
          const float* __restrict__ bih,
          const float* __restrict__ bhh,
          const float* __restrict__ Wfc,
          const float* __restrict__ bfc,
          float* __restrict__ out,
          unsigned int* __restrict__ tags,   // [16 groups][16 producers] padded x4
          unsigned int* __restrict__ hb)     // plane-format h double buffer
{
  const int tid = threadIdx.x;
  const int w   = tid >> 6;
  const int l   = tid & 63;
  const int lr  = l & 15;     // A row / B,D col
  const int lk  = l >> 4;     // k subgroup

  const int bi  = blockIdx.x & (NGROUP - 1);
  const int gj  = blockIdx.x / NGROUP;
  const int r0  = bi * 16;
  const int hc0 = gj * 32;
  const int oc0 = gj * 16;    // out-col base == h pair-word base

  // ---- persistent fp16 split-2 weight fragments, merged K = [h 16 tiles | x 8 tiles] ----
  half8 wz1[24][2], wz2[24][2];
#pragma unroll
  for (int kk = 0; kk < 24; ++kk)
#pragma unroll
    for (int nt = 0; nt < 2; ++nt) {
      int g = w * HDIM + hc0 + nt * 16 + lr;
      const float* src = (kk < 16)
          ? (Whh + (size_t)g * HDIM + kk * 32 + lk * 8)
          : (Wih + (size_t)g * IDIM + (kk - 16) * 32 + lk * 8);
      const f32x4 va = *(const f32x4*)src;
      const f32x4 vb = *(const f32x4*)(src + 4);
#pragma unroll
      for (int j = 0; j < 4; ++j) { _Float16 h, lo; split_f(va[j], h, lo); wz1[kk][nt][j] = h; wz2[kk][nt][j] = lo; }
#pragma unroll
      for (int j = 0; j < 4; ++j) { _Float16 h, lo; split_f(vb[j], h, lo); wz1[kk][nt][4 + j] = h; wz2[kk][nt][4 + j] = lo; }
    }
  half8 wfc1[4];   // FC weight hi-level only (error non-recurrent)
#pragma unroll
  for (int q = 0; q < 4; ++q) {
    const float* src = Wfc + (size_t)(oc0 + lr) * HDIM + (w * 4 + q) * 32 + lk * 8;
#pragma unroll
    for (int j = 0; j < 8; ++j) { _Float16 h, lo; split_f(src[j], h, lo); wfc1[q][j] = h; }
  }
  float gb[2];
#pragma unroll
  for (int nt = 0; nt < 2; ++nt) {
    int g = w * HDIM + hc0 + nt * 16 + lr;
    gb[nt] = bih[g] + bhh[g];
  }

  const int rrow = tid >> 4;
  const int rcp  = tid & 15;
  const float fcb = bfc[oc0 + rcp];

  __shared__ unsigned int z1[16][ZW];   // hi plane: [h 256 u32 | x 128 u32] fp16 pairs
  __shared__ unsigned int z2[16][ZW];   // lo plane (2^12-scaled residual)
  __shared__ float lds_g[4][16][32];
  __shared__ float lds_fc[4][16][16];
  __shared__ float lds_c[16][32];

  lds_c[rrow][2 * rcp]     = 0.f;
  lds_c[rrow][2 * rcp + 1] = 0.f;

  const int srow = tid & 15;   // staging row
  const int schk = tid >> 4;   // staging chunk == producer index
  unsigned int* mytag = tags + (bi * 16 + schk) * 4;

#pragma unroll 1
  for (int t = 0; t < SEQ; ++t) {
    // ---- stage x[t] first (independent of h; cached loads; split here) ----
    {
      const float* xt = xs + (size_t)t * BATCH * IDIM + (size_t)(r0 + srow) * IDIM + schk * 16;
#pragma unroll
      for (int i = 0; i < 8; ++i) {
        _Float16 h0, l0, h1, l1;
        split_f(xt[2 * i],     h0, l0);
        split_f(xt[2 * i + 1], h1, l1);
        int c = 256 + schk * 8 + i;
        z1[srow][c] = (unsigned int)hbits(h0) | ((unsigned int)hbits(h1) << 16);
        z2[srow][c] = (unsigned int)hbits(l0) | ((unsigned int)hbits(l1) << 16);
      }
    }

    // ---- per-thread: poll own producer's tag, then burst its pre-split slice ----
    if (t > 0) {
      wait_tag(mytag, (unsigned int)t);
      const unsigned int* p1 = hb + ((unsigned)((t - 1) & 1)) * HBUFSTRIDE
                             + (unsigned)(r0 + srow) * 256u + (unsigned)(schk * 16);
      uint4v a[4], b[4];
      ld_2x64_sys(p1, p1 + HPLANE, a, b);
#pragma unroll
      for (int j = 0; j < 4; ++j)
#pragma unroll
        for (int e = 0; e < 4; ++e) {
          z1[srow][schk * 16 + 4 * j + e] = a[j][e];
          z2[srow][schk * 16 + 4 * j + e] = b[j][e];
        }
    } else {
#pragma unroll
      for (int i = 0; i < 16; ++i) {
        z1[srow][schk * 16 + i] = 0u;
        z2[srow][schk * 16 + i] = 0u;
      }
    }
    __syncthreads();

    // ---- gates: 24 K-tiles x 2 n-tiles x 3 split-products ----
    f32x4 ga0 = {gb[0], gb[0], gb[0], gb[0]};
    f32x4 ga1 = {gb[1], gb[1], gb[1], gb[1]};
    f32x4 gl0 = {0.f, 0.f, 0.f, 0.f};
    f32x4 gl1 = {0.f, 0.f, 0.f, 0.f};
    const unsigned short* zr1 = (const unsigned short*)&z1[lr][0];
    const unsigned short* zr2 = (const unsigned short*)&z2[lr][0];
#pragma unroll
    for (int kk = 0; kk < 24; ++kk) {
      half8 a1 = *(const half8*)(zr1 + kk * 32 + lk * 8);
      half8 a2 = *(const half8*)(zr2 + kk * 32 + lk * 8);
      ga0 = mfma_h(a1, wz1[kk][0], ga0);
      gl0 = mfma_h(a2, wz1[kk][0], gl0);
      gl0 = mfma_h(a1, wz2[kk][0], gl0);
      ga1 = mfma_h(a1, wz1[kk][1], ga1);
      gl1 = mfma_h(a2, wz1[kk][1], gl1);
      gl1 = mfma_h(a1, wz2[kk][1], gl1);
    }

    // ---- FC head on h[t-1] (K-quarter per wave) ----
    f32x4 f1a = {0.f, 0.f, 0.f, 0.f};
    f32x4 f2a = {0.f, 0.f, 0.f, 0.f};
    if (t > 0) {
#pragma unroll
      for (int q = 0; q < 4; ++q) {
        int kk = w * 4 + q;
        half8 a1 = *(const half8*)(zr1 + kk * 32 + lk * 8);
        half8 a2 = *(const half8*)(zr2 + kk * 32 + lk * 8);
        f1a = mfma_h(a1, wfc1[q], f1a);
        f2a = mfma_h(a2, wfc1[q], f2a);
      }
    }

    // ---- fold + exchange ----
#pragma unroll
    for (int j = 0; j < 4; ++j) {
      lds_g[w][lk * 4 + j][lr]      = ga0[j] + gl0[j] * H_INV;
      lds_g[w][lk * 4 + j][16 + lr] = ga1[j] + gl1[j] * H_INV;
      lds_fc[w][lk * 4 + j][lr]     = f1a[j] + f2a[j] * H_INV;
    }
    __syncthreads();

    // ---- recombine ----
    float hn[2], cn[2];
#pragma unroll
    for (int q = 0; q < 2; ++q) {
      int c = 2 * rcp + q;
      float ig = sigm(lds_g[0][rrow][c]);
      float fg = sigm(lds_g[1][rrow][c]);
      float gg = tanh_f(lds_g[2][rrow][c]);
      float og = sigm(lds_g[3][rrow][c]);
      float cc = fg * lds_c[rrow][c] + ig * gg;
      lds_c[rrow][c] = cc;
      cn[q] = cc;
      hn[q] = og * tanh_f(cc);
    }

    // ---- publish h[t] PRE-SPLIT (planes), drain, barrier, tags ----
    {
      _Float16 h0h, h0l, h1h, h1l;
      split_f(hn[0], h0h, h0l);
      split_f(hn[1], h1h, h1l);
      unsigned int hiw = (unsigned int)hbits(h0h) | ((unsigned int)hbits(h1h) << 16);
      unsigned int low = (unsigned int)hbits(h0l) | ((unsigned int)hbits(h1l) << 16);
      unsigned int wi = ((unsigned)(t & 1)) * HBUFSTRIDE
                      + (unsigned)(r0 + rrow) * 256u + (unsigned)(oc0 + rcp);
      st_sys_u32(hb + wi,          hiw);
      st_sys_u32(hb + HPLANE + wi, low);
    }
    asm volatile("s_waitcnt vmcnt(0)" ::: "memory");  // payload at coherence point
    __syncthreads();                                   // all waves drained
    if (tid < 16) st_sys_u32(tags + (bi * 16 + tid) * 4, (unsigned int)(t + 1));

    // ---- out stores off the critical path ----
    if (t > 0) {
      float o = lds_fc[0][rrow][rcp] + lds_fc[1][rrow][rcp]
              + lds_fc[2][rrow][rcp] + lds_fc[3][rrow][rcp] + fcb;
      out[((size_t)(t - 1) * BATCH + (r0 + rrow)) * ODIM + oc0 + rcp] = o;
    }
    if (t == SEQ - 1) {
#pragma unroll
      for (int q = 0; q < 2; ++q) {
        size_t hi_ = (size_t)(r0 + rrow) * HDIM + hc0 + 2 * rcp + q;
        out[HF_OFF + hi_] = hn[q];
        out[CF_OFF + hi_] = cn[q];
      }
    }
  }

  // ---- tail: out[SEQ-1] from h[SEQ-1] ----
  {
    wait_tag(mytag, (unsigned int)SEQ);
    const unsigned int* p1 = hb + ((unsigned)((SEQ - 1) & 1)) * HBUFSTRIDE
                           + (unsigned)(r0 + srow) * 256u + (unsigned)(schk * 16);
    uint4v a[4], b[4];
    ld_2x64_sys(p1, p1 + HPLANE, a, b);
#pragma unroll
    for (int j = 0; j < 4; ++j)
#pragma unroll
      for (int e = 0; e < 4; ++e) {
        z1[srow][schk * 16 + 4 * j + e] = a[j][e];
        z2[srow][schk * 16 + 4 * j + e] = b[j][e];
      }
    __syncthreads();
    f32x4 f1a = {0.f, 0.f, 0.f, 0.f};
    f32x4 f2a = {0.f, 0.f, 0.f, 0.f};
    const unsigned short* zr1 = (const unsigned short*)&z1[lr][0];
    const unsigned short* zr2 = (const unsigned short*)&z2[lr][0];
#pragma unroll
    for (int q = 0; q < 4; ++q) {
      int kk = w * 4 + q;
      half8 a1 = *(const half8*)(zr1 + kk * 32 + lk * 8);
      half8 a2 = *(const half8*)(zr2 + kk * 32 + lk * 8);
      f1a = mfma_h(a1, wfc1[q], f1a);
      f2a = mfma_h(a2, wfc1[q], f2a);
    }
#pragma unroll
    for (int j = 0; j < 4; ++j)
      lds_fc[w][lk * 4 + j][lr] = f1a[j] + f2a[j] * H_INV;
    __syncthreads();
    float o = lds_fc[0][rrow][rcp] + lds_fc[1][rrow][rcp]
            + lds_fc[2][rrow][rcp] + lds_fc[3][rrow][rcp] + fcb;
    out[((size_t)(SEQ - 1) * BATCH + (r0 + rrow)) * ODIM + oc0 + rcp] = o;
  }
}

extern "C" void kernel_launch(void* const* d_in, const int* in_sizes, int n_in,
                              void* d_out, int out_size, void* d_ws, size_t ws_size,
                              hipStream_t stream)
{
  const float* xs  = (const float*)d_in[0];
  const float* wih = (const float*)d_in[1];
  const float* whh = (const float*)d_in[2];
  const float* bi_ = (const float*)d_in[3];
  const float* bh_ = (const float*)d_in[4];
  const float* wfc = (const float*)d_in[5];
  const float* bf_ = (const float*)d_in[6];
  float* out = (float*)d_out;

  unsigned int* tags = (unsigned int*)d_ws;                    // 4 KB tag area
  unsigned int* hb   = (unsigned int*)((char*)d_ws + 4096);    // 1 MB plane dbuf

  hipMemsetAsync(d_ws, 0, 4096, stream);  // reset tags each call

  lstm_mfma<<<dim3(NGROUP * GBLK), dim3(256), 0, stream>>>(
      xs, wih, whh, bi_, bh_, wfc, bf_, out, tags, hb);
}

// Round 9
// 4891.073 us; speedup vs baseline: 7.5835x; 1.0133x over previous
//
#include <hip/hip_runtime.h>
#include <math.h>

#define SEQ   512
#define BATCH 256
#define IDIM  256
#define HDIM  512
#define ODIM  256
#define NGROUP 16   // batch groups (bi), 16 rows each
#define GBLK   16   // blocks per group (gj), 32 h-cols each

#define OUT_ELEMS ((size_t)SEQ * BATCH * ODIM)
#define HF_OFF OUT_ELEMS
#define CF_OFF (OUT_ELEMS + (size_t)BATCH * HDIM)

// h exchange: 3-buffer ring, each buf = [2 planes][256 rows][256 u32 fp16-pair words]
#define HPLANE 65536u
#define BUFW   131072u
#define SENT   0x7F7F7F7Fu        // fp16 NaN|NaN — unreachable for |h|<1 payload
#define SPIN_TIMEOUT 200000000ull

#define H_SCALE 4096.0f
#define H_INV   2.44140625e-4f   // 2^-12
#define HMIN    6.104e-5f        // fp16 min normal
#define ZW      390              // u32 row stride of z planes (bank-spread)

typedef __attribute__((ext_vector_type(8))) _Float16 half8;
typedef __attribute__((ext_vector_type(4))) float f32x4;
typedef __attribute__((ext_vector_type(4))) unsigned int uint4v;

__device__ __forceinline__ unsigned short hbits(_Float16 h) {
  return __builtin_bit_cast(unsigned short, h);
}

__device__ __forceinline__ f32x4 mfma_h(half8 a, half8 b, f32x4 c) {
  return __builtin_amdgcn_mfma_f32_16x16x32_f16(a, b, c, 0, 0, 0);
}

// ---- system-coherent (cache-bypassing) accessors ----
__device__ __forceinline__ void st_sys_u32(unsigned int* p, unsigned int d) {
  asm volatile("global_store_dword %0, %1, off sc0 sc1"
               : : "v"((unsigned long long)p), "v"(d) : "memory");
}

// Two 64B plane slices (hi, lo) in one burst, single vmcnt(0).
__device__ __forceinline__ void ld_2x64_sys(const unsigned int* p0, const unsigned int* p1,
                                            uint4v a[4], uint4v b[4]) {
  asm volatile(
      "global_load_dwordx4 %0, %8, off sc0 sc1\n\t"
      "global_load_dwordx4 %1, %8, off offset:16 sc0 sc1\n\t"
      "global_load_dwordx4 %2, %8, off offset:32 sc0 sc1\n\t"
      "global_load_dwordx4 %3, %8, off offset:48 sc0 sc1\n\t"
      "global_load_dwordx4 %4, %9, off sc0 sc1\n\t"
      "global_load_dwordx4 %5, %9, off offset:16 sc0 sc1\n\t"
      "global_load_dwordx4 %6, %9, off offset:32 sc0 sc1\n\t"
      "global_load_dwordx4 %7, %9, off offset:48 sc0 sc1\n\t"
      "s_waitcnt vmcnt(0)"
      : "=&v"(a[0]), "=&v"(a[1]), "=&v"(a[2]), "=&v"(a[3]),
        "=&v"(b[0]), "=&v"(b[1]), "=&v"(b[2]), "=&v"(b[3])
      : "v"((unsigned long long)p0), "v"((unsigned long long)p1)
      : "memory");
}

// Poll the 32-word slice until every word is non-sentinel (each word is
// individually valid the moment it is non-sentinel; 32-bit stores are atomic).
__device__ __forceinline__ void poll_slab(const unsigned int* p0, const unsigned int* p1,
                                          uint4v a[4], uint4v b[4]) {
  unsigned long long t0 = __builtin_amdgcn_s_memrealtime();
  for (;;) {
    ld_2x64_sys(p0, p1, a, b);
    unsigned int bad = 0;
#pragma unroll
    for (int j = 0; j < 4; ++j)
#pragma unroll
      for (int e = 0; e < 4; ++e) {
        bad |= (a[j][e] == SENT);
        bad |= (b[j][e] == SENT);
      }
    if (!bad) return;
    if (__builtin_amdgcn_s_memrealtime() - t0 > SPIN_TIMEOUT) return;  // diagnostic bail
  }
}

// Scaled split-2: v = hi + lo*2^-12 + O(2^-23 * v).
__device__ __forceinline__ void split_f(float f, _Float16 &hi, _Float16 &lo) {
  _Float16 a = (_Float16)0.f;
  if (fabsf(f) >= HMIN) a = (_Float16)f;
  float f1 = (float)a;
  hi = a;
  lo = (_Float16)((f - f1) * H_SCALE);
}

__device__ __forceinline__ float sigm(float x)   { return 1.f / (1.f + expf(-x)); }
__device__ __forceinline__ float tanh_f(float x) { return 1.f - 2.f / (expf(2.f * x) + 1.f); }

// Protocol v3: sentinel-validated payload, 3-buffer ring, no tags, no
// producer drain-after-publish. grid=256, block=256=4 waves.
__global__ void __launch_bounds__(256, 1)
lstm_mfma(const float* __restrict__ xs,
          const float* __restrict__ Wih,
          const float* __restrict__ Whh,
          const float* __restrict__ bih,
          const float* __restrict__ bhh,
          const float* __restrict__ Wfc,
          const float* __restrict__ bfc,
          float* __restrict__ out,
          unsigned int* __restrict__ hb)   // 3 x BUFW ring
{
  const int tid = threadIdx.x;
  const int w   = tid >> 6;
  const int l   = tid & 63;
  const int lr  = l & 15;     // A row / B,D col
  const int lk  = l >> 4;     // k subgroup

  const int bi  = blockIdx.x & (NGROUP - 1);
  const int gj  = blockIdx.x / NGROUP;
  const int r0  = bi * 16;
  const int hc0 = gj * 32;
  const int oc0 = gj * 16;    // out-col base == h pair-word base

  // ---- persistent fp16 split-2 weight fragments, merged K = [h 16 tiles | x 8 tiles] ----
  half8 wz1[24][2], wz2[24][2];
#pragma unroll
  for (int kk = 0; kk < 24; ++kk)
#pragma unroll
    for (int nt = 0; nt < 2; ++nt) {
      int g = w * HDIM + hc0 + nt * 16 + lr;
      const float* src = (kk < 16)
          ? (Whh + (size_t)g * HDIM + kk * 32 + lk * 8)
          : (Wih + (size_t)g * IDIM + (kk - 16) * 32 + lk * 8);
      const f32x4 va = *(const f32x4*)src;
      const f32x4 vb = *(const f32x4*)(src + 4);
#pragma unroll
      for (int j = 0; j < 4; ++j) { _Float16 h, lo; split_f(va[j], h, lo); wz1[kk][nt][j] = h; wz2[kk][nt][j] = lo; }
#pragma unroll
      for (int j = 0; j < 4; ++j) { _Float16 h, lo; split_f(vb[j], h, lo); wz1[kk][nt][4 + j] = h; wz2[kk][nt][4 + j] = lo; }
    }
  half8 wfc1[4];   // FC weight hi-level only (error non-recurrent)
#pragma unroll
  for (int q = 0; q < 4; ++q) {
    const float* src = Wfc + (size_t)(oc0 + lr) * HDIM + (w * 4 + q) * 32 + lk * 8;
#pragma unroll
    for (int j = 0; j < 8; ++j) { _Float16 h, lo; split_f(src[j], h, lo); wfc1[q][j] = h; }
  }
  float gb[2];
#pragma unroll
  for (int nt = 0; nt < 2; ++nt) {
    int g = w * HDIM + hc0 + nt * 16 + lr;
    gb[nt] = bih[g] + bhh[g];
  }

  const int rrow = tid >> 4;
  const int rcp  = tid & 15;
  const float fcb = bfc[oc0 + rcp];
  const unsigned int wi_row = (unsigned)(r0 + rrow) * 256u + (unsigned)(oc0 + rcp);

  __shared__ unsigned int z1[16][ZW];   // hi plane: [h 256 u32 | x 128 u32] fp16 pairs
  __shared__ unsigned int z2[16][ZW];   // lo plane (2^12-scaled residual)
  __shared__ float lds_g[4][16][32];
  __shared__ float lds_fc[4][16][16];
  __shared__ float lds_c[16][32];

  lds_c[rrow][2 * rcp]     = 0.f;
  lds_c[rrow][2 * rcp + 1] = 0.f;

  const int srow = tid & 15;   // staging row
  const int schk = tid >> 4;   // staging chunk (== producer gj of that slice)

  // ring: at step t read pR (h[t-1]), write pW (h[t]), sentinel pS (future h[t+1])
  unsigned int* pR = hb + 2u * BUFW;
  unsigned int* pW = hb;
  unsigned int* pS = hb + BUFW;

#pragma unroll 1
  for (int t = 0; t < SEQ; ++t) {
    // ---- stage x[t] (vectorized loads, split, LDS) — independent of h ----
    {
      const float* xt = xs + (size_t)t * BATCH * IDIM + (size_t)(r0 + srow) * IDIM + schk * 16;
#pragma unroll
      for (int v4 = 0; v4 < 4; ++v4) {
        f32x4 xv = *(const f32x4*)(xt + 4 * v4);
        _Float16 h0, l0, h1, l1, h2, l2, h3, l3;
        split_f(xv[0], h0, l0); split_f(xv[1], h1, l1);
        split_f(xv[2], h2, l2); split_f(xv[3], h3, l3);
        int c = 256 + schk * 8 + 2 * v4;
        z1[srow][c]     = (unsigned int)hbits(h0) | ((unsigned int)hbits(h1) << 16);
        z2[srow][c]     = (unsigned int)hbits(l0) | ((unsigned int)hbits(l1) << 16);
        z1[srow][c + 1] = (unsigned int)hbits(h2) | ((unsigned int)hbits(h3) << 16);
        z2[srow][c + 1] = (unsigned int)hbits(l2) | ((unsigned int)hbits(l3) << 16);
      }
    }
    __syncthreads();   // sync1: x staged (also closes prev step everywhere)

    // ---- x-part of gates first: overlaps producers' publish latency ----
    f32x4 ga0 = {gb[0], gb[0], gb[0], gb[0]};
    f32x4 ga1 = {gb[1], gb[1], gb[1], gb[1]};
    f32x4 gl0 = {0.f, 0.f, 0.f, 0.f};
    f32x4 gl1 = {0.f, 0.f, 0.f, 0.f};
    const unsigned short* zr1 = (const unsigned short*)&z1[lr][0];
    const unsigned short* zr2 = (const unsigned short*)&z2[lr][0];
#pragma unroll
    for (int kk = 16; kk < 24; ++kk) {
      half8 a1 = *(const half8*)(zr1 + kk * 32 + lk * 8);
      half8 a2 = *(const half8*)(zr2 + kk * 32 + lk * 8);
      ga0 = mfma_h(a1, wz1[kk][0], ga0);
      gl0 = mfma_h(a2, wz1[kk][0], gl0);
      gl0 = mfma_h(a1, wz2[kk][0], gl0);
      ga1 = mfma_h(a1, wz1[kk][1], ga1);
      gl1 = mfma_h(a2, wz1[kk][1], gl1);
      gl1 = mfma_h(a1, wz2[kk][1], gl1);
    }

    // ---- poll + stage h[t-1]; sentinel own slice of pS ----
    if (t > 0) {
      const unsigned int* p1 = pR + (unsigned)(r0 + srow) * 256u + (unsigned)(schk * 16);
      uint4v a[4], b[4];
      poll_slab(p1, p1 + HPLANE, a, b);
#pragma unroll
      for (int j = 0; j < 4; ++j)
#pragma unroll
        for (int e = 0; e < 4; ++e) {
          z1[srow][schk * 16 + 4 * j + e] = a[j][e];
          z2[srow][schk * 16 + 4 * j + e] = b[j][e];
        }
    }
    // sentinel the words this thread will publish h[t+1] into (ordered before
    // the h[t] publish by the vmcnt(0) below; see 3-buffer proof in notes)
    st_sys_u32(pS + wi_row,          SENT);
    st_sys_u32(pS + HPLANE + wi_row, SENT);
    __syncthreads();   // sync2: h staged

    // ---- h-part of gates ----
    if (t > 0) {
#pragma unroll
      for (int kk = 0; kk < 16; ++kk) {
        half8 a1 = *(const half8*)(zr1 + kk * 32 + lk * 8);
        half8 a2 = *(const half8*)(zr2 + kk * 32 + lk * 8);
        ga0 = mfma_h(a1, wz1[kk][0], ga0);
        gl0 = mfma_h(a2, wz1[kk][0], gl0);
        gl0 = mfma_h(a1, wz2[kk][0], gl0);
        ga1 = mfma_h(a1, wz1[kk][1], ga1);
        gl1 = mfma_h(a2, wz1[kk][1], gl1);
        gl1 = mfma_h(a1, wz2[kk][1], gl1);
      }
    }

    // ---- FC head on h[t-1] (K-quarter per wave) ----
    f32x4 f1a = {0.f, 0.f, 0.f, 0.f};
    f32x4 f2a = {0.f, 0.f, 0.f, 0.f};
    if (t > 0) {
#pragma unroll
      for (int q = 0; q < 4; ++q) {
        int kk = w * 4 + q;
        half8 a1 = *(const half8*)(zr1 + kk * 32 + lk * 8);
        half8 a2 = *(const half8*)(zr2 + kk * 32 + lk * 8);
        f1a = mfma_h(a1, wfc1[q], f1a);
        f2a = mfma_h(a2, wfc1[q], f2a);
      }
    }

    // ---- fold + exchange ----
#pragma unroll
    for (int j = 0; j < 4; ++j) {
      lds_g[w][lk * 4 + j][lr]      = ga0[j] + gl0[j] * H_INV;
      lds_g[w][lk * 4 + j][16 + lr] = ga1[j] + gl1[j] * H_INV;
      lds_fc[w][lk * 4 + j][lr]     = f1a[j] + f2a[j] * H_INV;
    }
    __syncthreads();   // sync3

    // ---- recombine ----
    float hn[2], cn[2];
#pragma unroll
    for (int q = 0; q < 2; ++q) {
      int c = 2 * rcp + q;
      float ig = sigm(lds_g[0][rrow][c]);
      float fg = sigm(lds_g[1][rrow][c]);
      float gg = tanh_f(lds_g[2][rrow][c]);
      float og = sigm(lds_g[3][rrow][c]);
      float cc = fg * lds_c[rrow][c] + ig * gg;
      lds_c[rrow][c] = cc;
      cn[q] = cc;
      hn[q] = og * tanh_f(cc);
    }

    // ---- drain (orders sentinels), publish h[t]; NO post-publish drain/sync ----
    asm volatile("s_waitcnt vmcnt(0)" ::: "memory");
    {
      _Float16 h0h, h0l, h1h, h1l;
      split_f(hn[0], h0h, h0l);
      split_f(hn[1], h1h, h1l);
      unsigned int hiw = (unsigned int)hbits(h0h) | ((unsigned int)hbits(h1h) << 16);
      unsigned int low = (unsigned int)hbits(h0l) | ((unsigned int)hbits(h1l) << 16);
      st_sys_u32(pW + wi_row,          hiw);
      st_sys_u32(pW + HPLANE + wi_row, low);
    }

    // ---- out stores off the critical path ----
    if (t > 0) {
      float o = lds_fc[0][rrow][rcp] + lds_fc[1][rrow][rcp]
              + lds_fc[2][rrow][rcp] + lds_fc[3][rrow][rcp] + fcb;
      out[((size_t)(t - 1) * BATCH + (r0 + rrow)) * ODIM + oc0 + rcp] = o;
    }
    if (t == SEQ - 1) {
#pragma unroll
      for (int q = 0; q < 2; ++q) {
        size_t hi_ = (size_t)(r0 + rrow) * HDIM + hc0 + 2 * rcp + q;
        out[HF_OFF + hi_] = hn[q];
        out[CF_OFF + hi_] = cn[q];
      }
    }

    // rotate ring
    unsigned int* tmp = pR; pR = pW; pW = pS; pS = tmp;
  }

  // ---- tail: out[SEQ-1] from h[SEQ-1] (pR now = buf[(SEQ-1)%3]) ----
  {
    const unsigned int* p1 = pR + (unsigned)(r0 + srow) * 256u + (unsigned)(schk * 16);
    uint4v a[4], b[4];
    poll_slab(p1, p1 + HPLANE, a, b);
#pragma unroll
    for (int j = 0; j < 4; ++j)
#pragma unroll
      for (int e = 0; e < 4; ++e) {
        z1[srow][schk * 16 + 4 * j + e] = a[j][e];
        z2[srow][schk * 16 + 4 * j + e] = b[j][e];
      }
    __syncthreads();
    f32x4 f1a = {0.f, 0.f, 0.f, 0.f};
    f32x4 f2a = {0.f, 0.f, 0.f, 0.f};
    const unsigned short* zr1 = (const unsigned short*)&z1[lr][0];
    const unsigned short* zr2 = (const unsigned short*)&z2[lr][0];
#pragma unroll
    for (int q = 0; q < 4; ++q) {
      int kk = w * 4 + q;
      half8 a1 = *(const half8*)(zr1 + kk * 32 + lk * 8);
      half8 a2 = *(const half8*)(zr2 + kk * 32 + lk * 8);
      f1a = mfma_h(a1, wfc1[q], f1a);
      f2a = mfma_h(a2, wfc1[q], f2a);
    }
#pragma unroll
    for (int j = 0; j < 4; ++j)
      lds_fc[w][lk * 4 + j][lr] = f1a[j] + f2a[j] * H_INV;
    __syncthreads();
    float o = lds_fc[0][rrow][rcp] + lds_fc[1][rrow][rcp]
            + lds_fc[2][rrow][rcp] + lds_fc[3][rrow][rcp] + fcb;
    out[((size_t)(SEQ - 1) * BATCH + (r0 + rrow)) * ODIM + oc0 + rcp] = o;
  }
}

extern "C" void kernel_launch(void* const* d_in, const int* in_sizes, int n_in,
                              void* d_out, int out_size, void* d_ws, size_t ws_size,
                              hipStream_t stream)
{
  const float* xs  = (const float*)d_in[0];
  const float* wih = (const float*)d_in[1];
  const float* whh = (const float*)d_in[2];
  const float* bi_ = (const float*)d_in[3];
  const float* bh_ = (const float*)d_in[4];
  const float* wfc = (const float*)d_in[5];
  const float* bf_ = (const float*)d_in[6];
  float* out = (float*)d_out;

  unsigned int* hb = (unsigned int*)d_ws;   // 1.5 MB: 3-buffer h ring

  // sentinel-fill the whole ring every call (0x7F7F7F7F per word)
  hipMemsetAsync(hb, 0x7F, (size_t)3 * BUFW * 4, stream);

  lstm_mfma<<<dim3(NGROUP * GBLK), dim3(256), 0, stream>>>(
      xs, wih, whh, bi_, bh_, wfc, bf_, out, hb);
}